// Round 2
// baseline (7317.565 us; speedup 1.0000x reference)
//
#include <hip/hip_runtime.h>
#include <hip/hip_bf16.h>
#include <cstdint>
#include <cstddef>

#define Bb 256
#define Tt 512
#define Dd 256
#define Uu 256
#define NJ 768  // 3*U

// ws layout (bytes):
//   flags  @ 0       : 256 int  (per-block step counters, zeroed per chunk)
//   len    @ 1024    : 256 int
//   mask   @ 2048    : B*T u8 = 131072
//   hbuf   @ 133120  : 2 * B * U f32 = 524288 (double-buffered h by step parity)
//   matx   @ 657408  : B * CT * 768 f32
#define WS_LEN   1024
#define WS_MASK  2048
#define WS_HBUF  133120
#define WS_MATX  657408

// ---------------------------------------------------------------- utilities
__global__ void zero_len_kernel(int* __restrict__ len) {
    if (threadIdx.x < Bb) len[threadIdx.x] = 0;
}

// blocks 0..127 zero hbuf (only when zeroH), block 128 zeroes flags
__global__ void init_scan_kernel(float* __restrict__ hbuf, int* __restrict__ flags, int zeroH) {
    if (blockIdx.x < 128) {
        if (zeroH) {
            float4* p = reinterpret_cast<float4*>(hbuf);
            p[(size_t)blockIdx.x * 256 + threadIdx.x] = make_float4(0.f, 0.f, 0.f, 0.f);
        }
    } else {
        flags[threadIdx.x] = 0;
    }
}

// one wave per (b,t) row; 4 rows per 256-thread block; grid = B*T/4
__global__ void mask_len_kernel(const float* __restrict__ codes,
                                unsigned char* __restrict__ mask,
                                int* __restrict__ len) {
    const int wave = threadIdx.x >> 6;
    const int lane = threadIdx.x & 63;
    const long long row = (long long)blockIdx.x * 4 + wave;  // b*T + t
    const float4* p = reinterpret_cast<const float4*>(codes + row * Dd);
    float4 v = p[lane];
    bool nz = (v.x != 0.f) || (v.y != 0.f) || (v.z != 0.f) || (v.w != 0.f);
    unsigned long long ball = __ballot(nz);
    if (lane == 0) {
        int b = (int)(row >> 9);
        int t = (int)(row & 511);
        unsigned char m = (ball != 0ull) ? 1 : 0;
        mask[row] = m;
        if (m) atomicMax(&len[b], t + 1);
    }
}

// ------------------------------------------------- phase 1: mat_x = codes@W + b0
__global__ __launch_bounds__(256)
void matx_gemm_kernel(const float* __restrict__ codes,
                      const float* __restrict__ W,
                      const float* __restrict__ b0,
                      float* __restrict__ matx,
                      int t0, int ctShift) {
    __shared__ float As[16][132];
    __shared__ float Bs[16][128];
    const int tid = threadIdx.x;
    const int tx = tid & 15, ty = tid >> 4;
    const int rbase = blockIdx.x * 128;
    const int cbase = blockIdx.y * 128;
    const int ctMask = (1 << ctShift) - 1;

    float acc[8][8];
#pragma unroll
    for (int i = 0; i < 8; ++i)
#pragma unroll
        for (int j = 0; j < 8; ++j) acc[i][j] = 0.f;

    for (int kt = 0; kt < 16; ++kt) {
        const int k0 = kt * 16;
        float4 av[2], bv[2];
#pragma unroll
        for (int q = 0; q < 2; ++q) {
            int L = tid + q * 256;
            int arow = L >> 2, kq = (L & 3) * 4;
            int r = rbase + arow;
            int b = r >> ctShift, ct = r & ctMask;
            size_t aoff = ((size_t)b * Tt + (size_t)(t0 + ct)) * Dd + (k0 + kq);
            av[q] = *reinterpret_cast<const float4*>(codes + aoff);
            int brow = L >> 5, c4 = (L & 31) * 4;
            bv[q] = *reinterpret_cast<const float4*>(W + (size_t)(k0 + brow) * NJ + cbase + c4);
        }
        __syncthreads();
#pragma unroll
        for (int q = 0; q < 2; ++q) {
            int L = tid + q * 256;
            int arow = L >> 2, kq = (L & 3) * 4;
            As[kq + 0][arow] = av[q].x;
            As[kq + 1][arow] = av[q].y;
            As[kq + 2][arow] = av[q].z;
            As[kq + 3][arow] = av[q].w;
            int brow = L >> 5, c4 = (L & 31) * 4;
            *reinterpret_cast<float4*>(&Bs[brow][c4]) = bv[q];
        }
        __syncthreads();
#pragma unroll
        for (int k = 0; k < 16; ++k) {
            float4 a0 = *reinterpret_cast<const float4*>(&As[k][ty * 4]);
            float4 a1 = *reinterpret_cast<const float4*>(&As[k][64 + ty * 4]);
            float4 c0 = *reinterpret_cast<const float4*>(&Bs[k][tx * 4]);
            float4 c1 = *reinterpret_cast<const float4*>(&Bs[k][64 + tx * 4]);
            float ar[8] = {a0.x, a0.y, a0.z, a0.w, a1.x, a1.y, a1.z, a1.w};
            float bc[8] = {c0.x, c0.y, c0.z, c0.w, c1.x, c1.y, c1.z, c1.w};
#pragma unroll
            for (int i = 0; i < 8; ++i)
#pragma unroll
                for (int j = 0; j < 8; ++j) acc[i][j] += ar[i] * bc[j];
        }
        __syncthreads();
    }
    float4 bias0 = *reinterpret_cast<const float4*>(b0 + cbase + tx * 4);
    float4 bias1 = *reinterpret_cast<const float4*>(b0 + cbase + 64 + tx * 4);
#pragma unroll
    for (int i = 0; i < 8; ++i) {
        int r = rbase + ((i < 4) ? (ty * 4 + i) : (64 + ty * 4 + (i - 4)));
        float* mp = matx + (size_t)r * NJ + cbase;
        float4 s0 = make_float4(acc[i][0] + bias0.x, acc[i][1] + bias0.y,
                                acc[i][2] + bias0.z, acc[i][3] + bias0.w);
        float4 s1 = make_float4(acc[i][4] + bias1.x, acc[i][5] + bias1.y,
                                acc[i][6] + bias1.z, acc[i][7] + bias1.w);
        *reinterpret_cast<float4*>(mp + tx * 4) = s0;
        *reinterpret_cast<float4*>(mp + 64 + tx * 4) = s1;
    }
}

// ------------------------------------------------- phase 2: sequential GRU scan
// 64 clusters x 4 slice-blocks. Cluster c owns batch rows 4c..4c+3; slice sl
// owns gate-column-triples colbase..colbase+63 (cols j, j+256, j+512).
// Thread (ksl = wave, lane) holds Uk[64ksl..64ksl+63][{col,col+256,col+512}]
// in 192 VGPRs. Per step: stage h (global->LDS), 768 FMAs, k-slice reduction
// via LDS, finalize gates, write h chunk to global, flag/spin sync w/ peers.
// Cluster c = blocks {c, c+64, c+128, c+192}: same XCD under round-robin
// dispatch (perf heuristic only; correctness via device-scope fences).
__global__ __launch_bounds__(256, 2)
void gru_scan_kernel(const float* __restrict__ matx,
                     const float* __restrict__ Uk,
                     const float* __restrict__ bias1,
                     const unsigned char* __restrict__ mask,
                     const int* __restrict__ len,
                     float* __restrict__ hbuf,
                     int* __restrict__ flags,
                     float* __restrict__ out,
                     int t0, int CT) {
    __shared__ float hsm[4][256];        // h_t for the cluster's 4 rows
    __shared__ float part[4][4][3][64];  // [ksl][row][gate][lane]

    const int tid = threadIdx.x;
    const int c  = blockIdx.x & 63;   // cluster
    const int sl = blockIdx.x >> 6;   // column slice 0..3
    const int colbase = sl << 6;
    const int ksl = tid >> 6;         // k-slice == wave id
    const int lane = tid & 63;
    const int col = colbase + lane;
    const int r0 = c << 2;

    // finalize mapping: thread -> (row, col)
    const int frow = tid >> 6;
    const int fl = tid & 63;
    const int fcol = colbase + fl;
    const int frowg = r0 + frow;

    const float bzv = bias1[fcol];
    const float brv = bias1[fcol + 256];
    const float bhv = bias1[fcol + 512];

    // ---- Uk into registers (192 VGPRs), one-time
    const float* ukp = Uk + (size_t)(ksl << 6) * NJ + col;
    float ukz[64], ukr[64], ukh[64];
#pragma unroll
    for (int k = 0; k < 64; ++k) {
        const float* p = ukp + (size_t)k * NJ;
        ukz[k] = p[0];
        ukr[k] = p[256];
        ukh[k] = p[512];
    }

    int lmax = max(max(len[r0], len[r0 + 1]), max(len[r0 + 2], len[r0 + 3]));
    int S = lmax - t0;
    if (S < 0) S = 0;
    if (S > CT) S = CT;

    int* cflags = flags + (c << 2);
    float hout = hbuf[(size_t)(t0 & 1) * (Bb * Uu) + (size_t)frowg * Uu + fcol];

    for (int s = 0; s < S; ++s) {
        const int par = (t0 + s) & 1;
        const int par2 = par ^ 1;
        if (s > 0) {
            if (tid == 0) {
                while (true) {
                    int f0 = __hip_atomic_load(cflags + 0, __ATOMIC_RELAXED, __HIP_MEMORY_SCOPE_AGENT);
                    int f1 = __hip_atomic_load(cflags + 1, __ATOMIC_RELAXED, __HIP_MEMORY_SCOPE_AGENT);
                    int f2 = __hip_atomic_load(cflags + 2, __ATOMIC_RELAXED, __HIP_MEMORY_SCOPE_AGENT);
                    int f3 = __hip_atomic_load(cflags + 3, __ATOMIC_RELAXED, __HIP_MEMORY_SCOPE_AGENT);
                    if (min(min(f0, f1), min(f2, f3)) >= s) break;
                    __builtin_amdgcn_s_sleep(2);
                }
            }
            __syncthreads();
            __builtin_amdgcn_fence(__ATOMIC_ACQUIRE, "agent");
        }
        // stage h_t: 256 threads load 4 rows x 256 cols (1 float4 each)
        {
            const float4* src = reinterpret_cast<const float4*>(
                hbuf + (size_t)par * (Bb * Uu) + (size_t)(r0 + ksl) * Uu);
            float4 v = src[lane];
            *reinterpret_cast<float4*>(&hsm[ksl][lane << 2]) = v;
        }
        // prefetch matx/mask for this step (independent of the h exchange;
        // latency hides under the FMA phase)
        const float* mrow = matx + ((size_t)frowg * CT + s) * NJ;
        float mxz = mrow[fcol];
        float mxr = mrow[fcol + 256];
        float mxh = mrow[fcol + 512];
        unsigned char m = mask[(size_t)frowg * Tt + (t0 + s)];
        __syncthreads();

        float acc[4][3];
#pragma unroll
        for (int r = 0; r < 4; ++r) { acc[r][0] = 0.f; acc[r][1] = 0.f; acc[r][2] = 0.f; }
#pragma unroll
        for (int r = 0; r < 4; ++r) {
#pragma unroll
            for (int kk = 0; kk < 16; ++kk) {
                float4 h4 = *reinterpret_cast<const float4*>(&hsm[r][(ksl << 6) + (kk << 2)]);
                float hv[4] = {h4.x, h4.y, h4.z, h4.w};
#pragma unroll
                for (int j = 0; j < 4; ++j) {
                    acc[r][0] += hv[j] * ukz[(kk << 2) + j];
                    acc[r][1] += hv[j] * ukr[(kk << 2) + j];
                    acc[r][2] += hv[j] * ukh[(kk << 2) + j];
                }
            }
        }
#pragma unroll
        for (int r = 0; r < 4; ++r) {
            part[ksl][r][0][lane] = acc[r][0];
            part[ksl][r][1][lane] = acc[r][1];
            part[ksl][r][2][lane] = acc[r][2];
        }
        __syncthreads();

        // finalize: sum k-slices, gates, h update
        float az = part[0][frow][0][fl] + part[1][frow][0][fl] + part[2][frow][0][fl] + part[3][frow][0][fl];
        float ar = part[0][frow][1][fl] + part[1][frow][1][fl] + part[2][frow][1][fl] + part[3][frow][1][fl];
        float ah = part[0][frow][2][fl] + part[1][frow][2][fl] + part[2][frow][2][fl] + part[3][frow][2][fl];
        float hprev = hsm[frow][fcol];
        float hn = hprev;
        if (m) {
            float z = 1.f / (1.f + expf(-(mxz + az + bzv)));
            float rr = 1.f / (1.f + expf(-(mxr + ar + brv)));
            float hc = tanhf(mxh + rr * (ah + bhv));
            hn = z * hprev + (1.f - z) * hc;
        }
        hout = hn;
        hbuf[(size_t)par2 * (Bb * Uu) + (size_t)frowg * Uu + fcol] = hn;
        __syncthreads();  // drains vmcnt: all h stores in L2 before fence
        if (tid == 0) {
            __builtin_amdgcn_fence(__ATOMIC_RELEASE, "agent");
            __hip_atomic_store(cflags + sl, s + 1, __ATOMIC_RELAXED, __HIP_MEMORY_SCOPE_AGENT);
        }
    }

    // exit: wait peers (so our parity-buffer rewrite can't race their last
    // stage-read), then persist h to both parities + out
    if (S > 0) {
        if (tid == 0) {
            while (true) {
                int f0 = __hip_atomic_load(cflags + 0, __ATOMIC_RELAXED, __HIP_MEMORY_SCOPE_AGENT);
                int f1 = __hip_atomic_load(cflags + 1, __ATOMIC_RELAXED, __HIP_MEMORY_SCOPE_AGENT);
                int f2 = __hip_atomic_load(cflags + 2, __ATOMIC_RELAXED, __HIP_MEMORY_SCOPE_AGENT);
                int f3 = __hip_atomic_load(cflags + 3, __ATOMIC_RELAXED, __HIP_MEMORY_SCOPE_AGENT);
                if (min(min(f0, f1), min(f2, f3)) >= S) break;
                __builtin_amdgcn_s_sleep(2);
            }
        }
        __syncthreads();
    }
    const int parF = (t0 + S) & 1;
    hbuf[(size_t)(parF ^ 1) * (Bb * Uu) + (size_t)frowg * Uu + fcol] = hout;
    hbuf[(size_t)parF * (Bb * Uu) + (size_t)frowg * Uu + fcol] = hout;
    out[(size_t)frowg * Uu + fcol] = hout;
}

// ---------------------------------------------------------------- launcher
extern "C" void kernel_launch(void* const* d_in, const int* in_sizes, int n_in,
                              void* d_out, int out_size, void* d_ws, size_t ws_size,
                              hipStream_t stream) {
    const float* codes = (const float*)d_in[0];
    const float* W     = (const float*)d_in[1];
    const float* Uk    = (const float*)d_in[2];
    const float* bias  = (const float*)d_in[3];   // [2][768]
    float* out = (float*)d_out;

    char* ws = (char*)d_ws;
    int* flags = (int*)ws;
    int* len = (int*)(ws + WS_LEN);
    unsigned char* mask = (unsigned char*)(ws + WS_MASK);
    float* hbuf = (float*)(ws + WS_HBUF);
    float* matx = (float*)(ws + WS_MATX);

    int CT = 1;
    for (int cc = 512; cc >= 1; cc >>= 1) {
        if ((size_t)WS_MATX + (size_t)cc * 786432ull <= ws_size) { CT = cc; break; }
    }
    int ctShift = __builtin_ctz((unsigned)CT);
    int nch = 512 / CT;

    zero_len_kernel<<<1, 256, 0, stream>>>(len);
    mask_len_kernel<<<Bb * Tt / 4, 256, 0, stream>>>(codes, mask, len);

    for (int c = 0; c < nch; ++c) {
        int t0 = c * CT;
        init_scan_kernel<<<129, 256, 0, stream>>>(hbuf, flags, (c == 0) ? 1 : 0);
        dim3 grid(2 * CT, 6);
        matx_gemm_kernel<<<grid, 256, 0, stream>>>(codes, W, bias, matx, t0, ctShift);
        gru_scan_kernel<<<256, 256, 0, stream>>>(matx, Uk, bias + NJ, mask, len,
                                                 hbuf, flags, out, t0, CT);
    }
}

// Round 3
// 1859.993 us; speedup vs baseline: 3.9342x; 3.9342x over previous
//
#include <hip/hip_runtime.h>
#include <hip/hip_bf16.h>
#include <cstdint>
#include <cstddef>

#define Bb 256
#define Tt 512
#define Dd 256
#define Uu 256
#define NJ 768  // 3*U

// ws layout (bytes): len @ 0 (1024) | mask @ 1024 (131072) | matx @ 132096
#define WS_MASK  1024
#define WS_MATX  132096

typedef _Float16 h2 __attribute__((ext_vector_type(2)));

#if defined(__has_builtin)
#if __has_builtin(__builtin_amdgcn_fdot2)
#define HAVE_FDOT2 1
#endif
#endif

__device__ __forceinline__ unsigned int pack2(float a, float b) {
    h2 v;
    v.x = (_Float16)a;
    v.y = (_Float16)b;
    return __builtin_bit_cast(unsigned int, v);
}

__device__ __forceinline__ float dot2_acc(unsigned int u, unsigned int hv, float acc) {
    h2 a = __builtin_bit_cast(h2, u);
    h2 b = __builtin_bit_cast(h2, hv);
#ifdef HAVE_FDOT2
    return __builtin_amdgcn_fdot2(a, b, acc, false);
#else
    return acc + (float)a.x * (float)b.x + (float)a.y * (float)b.y;
#endif
}

// ---------------------------------------------------------------- utilities
__global__ void zero_len_kernel(int* __restrict__ len) {
    if (threadIdx.x < Bb) len[threadIdx.x] = 0;
}

// one wave per (b,t) row; 4 rows per 256-thread block; grid = B*T/4
__global__ void mask_len_kernel(const float* __restrict__ codes,
                                unsigned char* __restrict__ mask,
                                int* __restrict__ len) {
    const int wave = threadIdx.x >> 6;
    const int lane = threadIdx.x & 63;
    const long long row = (long long)blockIdx.x * 4 + wave;  // b*T + t
    const float4* p = reinterpret_cast<const float4*>(codes + row * Dd);
    float4 v = p[lane];
    bool nz = (v.x != 0.f) || (v.y != 0.f) || (v.z != 0.f) || (v.w != 0.f);
    unsigned long long ball = __ballot(nz);
    if (lane == 0) {
        int b = (int)(row >> 9);
        int t = (int)(row & 511);
        unsigned char m = (ball != 0ull) ? 1 : 0;
        mask[row] = m;
        if (m) atomicMax(&len[b], t + 1);
    }
}

// ------------------------------------------------- phase 1: mat_x = codes@W + b0
__global__ __launch_bounds__(256)
void matx_gemm_kernel(const float* __restrict__ codes,
                      const float* __restrict__ W,
                      const float* __restrict__ b0,
                      float* __restrict__ matx,
                      int t0, int ctShift) {
    __shared__ float As[16][132];
    __shared__ float Bs[16][128];
    const int tid = threadIdx.x;
    const int tx = tid & 15, ty = tid >> 4;
    const int rbase = blockIdx.x * 128;
    const int cbase = blockIdx.y * 128;
    const int ctMask = (1 << ctShift) - 1;

    float acc[8][8];
#pragma unroll
    for (int i = 0; i < 8; ++i)
#pragma unroll
        for (int j = 0; j < 8; ++j) acc[i][j] = 0.f;

    for (int kt = 0; kt < 16; ++kt) {
        const int k0 = kt * 16;
        float4 av[2], bv[2];
#pragma unroll
        for (int q = 0; q < 2; ++q) {
            int L = tid + q * 256;
            int arow = L >> 2, kq = (L & 3) * 4;
            int r = rbase + arow;
            int b = r >> ctShift, ct = r & ctMask;
            size_t aoff = ((size_t)b * Tt + (size_t)(t0 + ct)) * Dd + (k0 + kq);
            av[q] = *reinterpret_cast<const float4*>(codes + aoff);
            int brow = L >> 5, c4 = (L & 31) * 4;
            bv[q] = *reinterpret_cast<const float4*>(W + (size_t)(k0 + brow) * NJ + cbase + c4);
        }
        __syncthreads();
#pragma unroll
        for (int q = 0; q < 2; ++q) {
            int L = tid + q * 256;
            int arow = L >> 2, kq = (L & 3) * 4;
            As[kq + 0][arow] = av[q].x;
            As[kq + 1][arow] = av[q].y;
            As[kq + 2][arow] = av[q].z;
            As[kq + 3][arow] = av[q].w;
            int brow = L >> 5, c4 = (L & 31) * 4;
            *reinterpret_cast<float4*>(&Bs[brow][c4]) = bv[q];
        }
        __syncthreads();
#pragma unroll
        for (int k = 0; k < 16; ++k) {
            float4 a0 = *reinterpret_cast<const float4*>(&As[k][ty * 4]);
            float4 a1 = *reinterpret_cast<const float4*>(&As[k][64 + ty * 4]);
            float4 c0 = *reinterpret_cast<const float4*>(&Bs[k][tx * 4]);
            float4 c1 = *reinterpret_cast<const float4*>(&Bs[k][64 + tx * 4]);
            float ar[8] = {a0.x, a0.y, a0.z, a0.w, a1.x, a1.y, a1.z, a1.w};
            float bc[8] = {c0.x, c0.y, c0.z, c0.w, c1.x, c1.y, c1.z, c1.w};
#pragma unroll
            for (int i = 0; i < 8; ++i)
#pragma unroll
                for (int j = 0; j < 8; ++j) acc[i][j] += ar[i] * bc[j];
        }
        __syncthreads();
    }
    float4 bias0 = *reinterpret_cast<const float4*>(b0 + cbase + tx * 4);
    float4 bias1 = *reinterpret_cast<const float4*>(b0 + cbase + 64 + tx * 4);
#pragma unroll
    for (int i = 0; i < 8; ++i) {
        int r = rbase + ((i < 4) ? (ty * 4 + i) : (64 + ty * 4 + (i - 4)));
        float* mp = matx + (size_t)r * NJ + cbase;
        float4 s0 = make_float4(acc[i][0] + bias0.x, acc[i][1] + bias0.y,
                                acc[i][2] + bias0.z, acc[i][3] + bias0.w);
        float4 s1 = make_float4(acc[i][4] + bias1.x, acc[i][5] + bias1.y,
                                acc[i][6] + bias1.z, acc[i][7] + bias1.w);
        *reinterpret_cast<float4*>(mp + tx * 4) = s0;
        *reinterpret_cast<float4*>(mp + 64 + tx * 4) = s1;
    }
}

// ------------------------------------------------- phase 2: sequential GRU scan
// One 512-thread block per batch row; 256 blocks = 1 block/CU; ZERO inter-block
// sync. Thread (col = tid&255, khalf = tid>>8) holds Uk[k in 128-slice][{col,
// col+256, col+512}] as 192 packed-fp16-pair VGPRs (pinned via asm so the
// compiler cannot re-materialize the loads — round-2 failure mode). h is 128
// packed-fp16 pairs in LDS (broadcast reads). Per step: 16x ds_read_b128 +
// 192x v_dot2_f32_f16 + 2-way partial reduce (LDS) + 4-wave finalize.
// h carry across chunks lives in d_out (chunk 0 never reads it).
__global__ __launch_bounds__(512, 2)
void gru_scan_kernel(const float* __restrict__ matx,
                     const float* __restrict__ Uk,
                     const float* __restrict__ bias1,
                     const unsigned char* __restrict__ mask,
                     const int* __restrict__ len,
                     float* __restrict__ out,
                     int t0, int CT) {
    __shared__ __align__(16) unsigned int hH[128];  // packed fp16 h pairs
    __shared__ float part[2][3][Uu];                // [khalf][gate][col]

    const int tid = threadIdx.x;
    const int b = blockIdx.x;
    const int col = tid & 255;
    const int khalf = tid >> 8;

    // ---- one-time: Uk slice -> 192 pinned VGPRs
    unsigned int ukz[64], ukr[64], ukh[64];
    {
        const float* base = Uk + (size_t)(khalf << 7) * NJ + col;
#pragma unroll
        for (int i = 0; i < 64; ++i) {
            const float* p0 = base + (size_t)(2 * i) * NJ;
            const float* p1 = base + (size_t)(2 * i + 1) * NJ;
            ukz[i] = pack2(p0[0], p1[0]);
            ukr[i] = pack2(p0[256], p1[256]);
            ukh[i] = pack2(p0[512], p1[512]);
        }
    }
#pragma unroll
    for (int i = 0; i < 64; ++i) {
        asm volatile("" : "+v"(ukz[i]), "+v"(ukr[i]), "+v"(ukh[i]));
    }

    int S = len[b] - t0;
    S = S < 0 ? 0 : (S > CT ? CT : S);

    float hprev = 0.f, bz = 0.f, br = 0.f, bh = 0.f;
    if (tid < 256) {
        hprev = (t0 == 0) ? 0.f : out[(size_t)b * Uu + col];
        bz = bias1[col];
        br = bias1[col + 256];
        bh = bias1[col + 512];
    }
    if (tid < 128) {
        float e0 = 0.f, e1 = 0.f;
        if (t0 != 0) {
            e0 = out[(size_t)b * Uu + 2 * tid];
            e1 = out[(size_t)b * Uu + 2 * tid + 1];
        }
        hH[tid] = pack2(e0, e1);
    }
    __syncthreads();

    const unsigned char* mrow_mask = mask + (size_t)b * Tt + t0;
    for (int s = 0; s < S; ++s) {
        // prefetch matx/mask early; latency hides under the dot phase
        float mxz = 0.f, mxr = 0.f, mxh = 0.f;
        unsigned char m = 0;
        if (tid < 256) {
            const float* mrow = matx + ((size_t)b * CT + s) * NJ;
            mxz = mrow[col];
            mxr = mrow[col + 256];
            mxh = mrow[col + 512];
            m = mrow_mask[s];
        }

        float az = 0.f, ar = 0.f, ah = 0.f;
        const unsigned int* hp = &hH[khalf << 6];
#pragma unroll
        for (int i = 0; i < 16; ++i) {
            uint4 q = *reinterpret_cast<const uint4*>(hp + (i << 2));
            az = dot2_acc(ukz[4 * i + 0], q.x, az);
            ar = dot2_acc(ukr[4 * i + 0], q.x, ar);
            ah = dot2_acc(ukh[4 * i + 0], q.x, ah);
            az = dot2_acc(ukz[4 * i + 1], q.y, az);
            ar = dot2_acc(ukr[4 * i + 1], q.y, ar);
            ah = dot2_acc(ukh[4 * i + 1], q.y, ah);
            az = dot2_acc(ukz[4 * i + 2], q.z, az);
            ar = dot2_acc(ukr[4 * i + 2], q.z, ar);
            ah = dot2_acc(ukh[4 * i + 2], q.z, ah);
            az = dot2_acc(ukz[4 * i + 3], q.w, az);
            ar = dot2_acc(ukr[4 * i + 3], q.w, ar);
            ah = dot2_acc(ukh[4 * i + 3], q.w, ah);
        }
        part[khalf][0][col] = az;
        part[khalf][1][col] = ar;
        part[khalf][2][col] = ah;
        __syncthreads();

        if (tid < 256) {
            float azs = part[0][0][col] + part[1][0][col];
            float ars = part[0][1][col] + part[1][1][col];
            float ahs = part[0][2][col] + part[1][2][col];
            float hn = hprev;
            if (m) {
                float z = 1.f / (1.f + expf(-(mxz + azs + bz)));
                float r = 1.f / (1.f + expf(-(mxr + ars + br)));
                float hc = tanhf(mxh + r * (ahs + bh));
                hn = z * hprev + (1.f - z) * hc;
            }
            hprev = hn;
            float ho = __shfl_xor(hn, 1);
            if (!(col & 1)) hH[col >> 1] = pack2(hn, ho);
        }
        __syncthreads();
    }

    if (tid < 256) out[(size_t)b * Uu + col] = hprev;
}

// ---------------------------------------------------------------- launcher
extern "C" void kernel_launch(void* const* d_in, const int* in_sizes, int n_in,
                              void* d_out, int out_size, void* d_ws, size_t ws_size,
                              hipStream_t stream) {
    const float* codes = (const float*)d_in[0];
    const float* W     = (const float*)d_in[1];
    const float* Uk    = (const float*)d_in[2];
    const float* bias  = (const float*)d_in[3];   // [2][768]
    float* out = (float*)d_out;

    char* ws = (char*)d_ws;
    int* len = (int*)ws;
    unsigned char* mask = (unsigned char*)(ws + WS_MASK);
    float* matx = (float*)(ws + WS_MATX);

    int CT = 1;
    for (int cc = 512; cc >= 1; cc >>= 1) {
        if ((size_t)WS_MATX + (size_t)cc * 786432ull <= ws_size) { CT = cc; break; }
    }
    int ctShift = __builtin_ctz((unsigned)CT);
    int nch = 512 / CT;

    zero_len_kernel<<<1, 256, 0, stream>>>(len);
    mask_len_kernel<<<Bb * Tt / 4, 256, 0, stream>>>(codes, mask, len);

    for (int c = 0; c < nch; ++c) {
        int t0 = c * CT;
        dim3 grid(2 * CT, 6);
        matx_gemm_kernel<<<grid, 256, 0, stream>>>(codes, W, bias, matx, t0, ctShift);
        gru_scan_kernel<<<Bb, 512, 0, stream>>>(matx, Uk, bias + NJ, mask, len,
                                                out, t0, CT);
    }
}

// Round 4
// 1445.880 us; speedup vs baseline: 5.0610x; 1.2864x over previous
//
#include <hip/hip_runtime.h>
#include <hip/hip_bf16.h>
#include <cstdint>
#include <cstddef>

#define Bb 256
#define Tt 512
#define Dd 256
#define Uu 256
#define NJ 768  // 3*U

// ws layout (bytes):
//   len  @ 0       : 1024
//   mask @ 1024    : 131072
//   ukp  @ 132096  : 3*128*256 uint = 393216  (packed fp16 Uk pairs)
//   matx @ 525312  : B * CT * 768 f32
#define WS_MASK  1024
#define WS_UKP   132096
#define WS_MATX  525312

typedef _Float16 h2 __attribute__((ext_vector_type(2)));
typedef short short8 __attribute__((ext_vector_type(8)));
typedef float f32x4 __attribute__((ext_vector_type(4)));

#if defined(__has_builtin)
#if __has_builtin(__builtin_amdgcn_fdot2)
#define HAVE_FDOT2 1
#endif
#endif

__device__ __forceinline__ unsigned int pack2(float a, float b) {
    h2 v;
    v.x = (_Float16)a;
    v.y = (_Float16)b;
    return __builtin_bit_cast(unsigned int, v);
}

__device__ __forceinline__ float dot2_acc(unsigned int u, unsigned int hv, float acc) {
    h2 a = __builtin_bit_cast(h2, u);
    h2 b = __builtin_bit_cast(h2, hv);
#ifdef HAVE_FDOT2
    return __builtin_amdgcn_fdot2(a, b, acc, false);
#else
    return acc + (float)a.x * (float)b.x + (float)a.y * (float)b.y;
#endif
}

// truncation split: x = hi + lo + O(2^-16 |x|)
__device__ __forceinline__ void bfsplit(float x, unsigned short& h, unsigned short& l) {
    unsigned u = __builtin_bit_cast(unsigned, x);
    h = (unsigned short)(u >> 16);
    float hf = __builtin_bit_cast(float, u & 0xFFFF0000u);
    float lf = x - hf;  // exact
    l = (unsigned short)(__builtin_bit_cast(unsigned, lf) >> 16);
}

union PK8 { unsigned short s[8]; uint4 v; };

// ---------------------------------------------------------------- utilities
__global__ void zero_len_kernel(int* __restrict__ len) {
    if (threadIdx.x < Bb) len[threadIdx.x] = 0;
}

// one wave per (b,t) row; 4 rows per 256-thread block; grid = B*T/4
__global__ void mask_len_kernel(const float* __restrict__ codes,
                                unsigned char* __restrict__ mask,
                                int* __restrict__ len) {
    const int wave = threadIdx.x >> 6;
    const int lane = threadIdx.x & 63;
    const long long row = (long long)blockIdx.x * 4 + wave;  // b*T + t
    const float4* p = reinterpret_cast<const float4*>(codes + row * Dd);
    float4 v = p[lane];
    bool nz = (v.x != 0.f) || (v.y != 0.f) || (v.z != 0.f) || (v.w != 0.f);
    unsigned long long ball = __ballot(nz);
    if (lane == 0) {
        int b = (int)(row >> 9);
        int t = (int)(row & 511);
        unsigned char m = (ball != 0ull) ? 1 : 0;
        mask[row] = m;
        if (m) atomicMax(&len[b], t + 1);
    }
}

// Uk fp32 [256][768] -> packed fp16 pairs ukp[g][kp][col], g=gate, kp=k/2
__global__ void uk_convert_kernel(const float* __restrict__ Uk,
                                  unsigned int* __restrict__ ukp) {
    int idx = blockIdx.x * 256 + threadIdx.x;  // 0..98303
    int col = idx & 255;
    int kp = (idx >> 8) & 127;
    int g = idx >> 15;
    float a = Uk[(size_t)(2 * kp) * NJ + (g << 8) + col];
    float b = Uk[(size_t)(2 * kp + 1) * NJ + (g << 8) + col];
    ukp[idx] = pack2(a, b);
}

// ------------------------------------------------- phase 1: mat_x = codes@W + b0
// bf16-split MFMA GEMM: C = ah@bh + ah@bl + al@bh (fp32 acc), 128x128 tile,
// BK=64, 4 waves. LDS holds A/B tiles in MFMA-fragment-linear layout: subtile
// (16x32) = 64 lanes x 16 B contiguous -> every ds_read_b128 is a contiguous
// 1 KB wave read (conflict-free). A-frag: lane=(row&15)|(kgroup<<4) holds 8
// consecutive k. B staged transposed (W is [k][n]); k-strided scalar loads hit
// L2 (W strip is tiny & hot).
__global__ __launch_bounds__(256, 2)
void matx_gemm_mfma(const float* __restrict__ codes,
                    const float* __restrict__ W,
                    const float* __restrict__ b0,
                    float* __restrict__ matx,
                    int t0, int ctShift) {
    __shared__ uint4 AH[1024], AL[1024], BH[1024], BL[1024];  // 16 KB each
    const int tid = threadIdx.x;
    const int w = tid >> 6, lane = tid & 63;
    const int rbase = blockIdx.x * 128, cbase = blockIdx.y * 128;
    const int ctMask = (1 << ctShift) - 1;

    f32x4 acc[4][4];
#pragma unroll
    for (int i = 0; i < 4; ++i)
#pragma unroll
        for (int j = 0; j < 4; ++j) acc[i][j] = (f32x4){0.f, 0.f, 0.f, 0.f};

    const int cB = tid & 127, kqB = tid >> 7;  // B-staging mapping

    for (int kt = 0; kt < 4; ++kt) {
        const int k0 = kt * 64;
        // ---- stage A (codes tile 128 rows x 64 k), convert fp32 -> bf16 hi/lo
#pragma unroll
        for (int u = 0; u < 4; ++u) {
            int L = u * 256 + tid;
            int r = L >> 3, o = L & 7;  // row in tile, k-octet
            int gr = rbase + r;
            size_t g = (size_t)(gr >> ctShift) * Tt + (size_t)(t0 + (gr & ctMask));
            const float* cp = codes + g * Dd + k0 + (o << 3);
            float4 f0 = *reinterpret_cast<const float4*>(cp);
            float4 f1 = *reinterpret_cast<const float4*>(cp + 4);
            float e[8] = {f0.x, f0.y, f0.z, f0.w, f1.x, f1.y, f1.z, f1.w};
            PK8 hp, lp;
#pragma unroll
            for (int i = 0; i < 8; ++i) bfsplit(e[i], hp.s[i], lp.s[i]);
            int idx = (((o >> 2) * 8 + (r >> 4)) << 6) + ((r & 15) | ((o & 3) << 4));
            AH[idx] = hp.v;
            AL[idx] = lp.v;
        }
        // ---- stage B (W tile 64 k x 128 n), transposed into fragment layout
        {
            PK8 ph[4], pl[4];
#pragma unroll
            for (int j = 0; j < 32; ++j) {
                float v = W[(size_t)(k0 + kqB * 32 + j) * NJ + cbase + cB];
                bfsplit(v, ph[j >> 3].s[j & 7], pl[j >> 3].s[j & 7]);
            }
#pragma unroll
            for (int o2 = 0; o2 < 4; ++o2) {
                int idx = ((kqB * 8 + (cB >> 4)) << 6) + ((cB & 15) | (o2 << 4));
                BH[idx] = ph[o2].v;
                BL[idx] = pl[o2].v;
            }
        }
        __syncthreads();
        // ---- compute: wave w owns 64x64 quadrant ((w&1), (w>>1))
        const int mbase = (w & 1) * 4, nbase = (w >> 1) * 4;
#pragma unroll
        for (int ki = 0; ki < 2; ++ki) {
            short8 ah[4], al2[4], bh[4], bl2[4];
#pragma unroll
            for (int x = 0; x < 4; ++x) {
                ah[x]  = *reinterpret_cast<const short8*>(&AH[((ki * 8 + mbase + x) << 6) + lane]);
                al2[x] = *reinterpret_cast<const short8*>(&AL[((ki * 8 + mbase + x) << 6) + lane]);
                bh[x]  = *reinterpret_cast<const short8*>(&BH[((ki * 8 + nbase + x) << 6) + lane]);
                bl2[x] = *reinterpret_cast<const short8*>(&BL[((ki * 8 + nbase + x) << 6) + lane]);
            }
#pragma unroll
            for (int mi = 0; mi < 4; ++mi)
#pragma unroll
                for (int ni = 0; ni < 4; ++ni) {
                    acc[mi][ni] = __builtin_amdgcn_mfma_f32_16x16x32_bf16(ah[mi], bh[ni], acc[mi][ni], 0, 0, 0);
                    acc[mi][ni] = __builtin_amdgcn_mfma_f32_16x16x32_bf16(ah[mi], bl2[ni], acc[mi][ni], 0, 0, 0);
                    acc[mi][ni] = __builtin_amdgcn_mfma_f32_16x16x32_bf16(al2[mi], bh[ni], acc[mi][ni], 0, 0, 0);
                }
        }
        __syncthreads();
    }
    // ---- epilogue: C/D layout col=lane&15, row=(lane>>4)*4+reg
    const int colq = lane & 15, rowq = (lane >> 4) * 4;
#pragma unroll
    for (int ni = 0; ni < 4; ++ni) {
        int cc = cbase + (w >> 1) * 64 + ni * 16 + colq;
        float bv = b0[cc];
#pragma unroll
        for (int mi = 0; mi < 4; ++mi) {
            int gr = rbase + (w & 1) * 64 + mi * 16 + rowq;
#pragma unroll
            for (int j = 0; j < 4; ++j)
                matx[(size_t)(gr + j) * NJ + cc] = acc[mi][ni][j] + bv;
        }
    }
}

// ------------------------------------------------- phase 2: sequential GRU scan
// One 512-thread block per batch row; no inter-block sync. Thread (col, khalf)
// holds Uk[k-slice][{col,col+256,col+512}] as 192 packed-fp16 uints, loaded
// DIRECTLY from pre-converted ukp (1 load -> 1 pinned reg; round-3 spill came
// from the fp32 load+pack transient pressure). h = 128 packed pairs in LDS.
__global__ __launch_bounds__(512, 2)
void gru_scan_kernel(const float* __restrict__ matx,
                     const unsigned int* __restrict__ ukp,
                     const float* __restrict__ bias1,
                     const unsigned char* __restrict__ mask,
                     const int* __restrict__ len,
                     float* __restrict__ out,
                     int t0, int CT) {
    __shared__ __align__(16) unsigned int hH[128];  // packed fp16 h pairs
    __shared__ float part[2][3][Uu];                // [khalf][gate][col]

    const int tid = threadIdx.x;
    const int b = blockIdx.x;
    const int col = tid & 255;
    const int khalf = tid >> 8;

    // ---- one-time: 192 direct uint loads -> pinned VGPRs
    unsigned int ukz[64], ukr[64], ukh[64];
    {
        const unsigned int* u0 = ukp + (khalf << 14) + col;
#pragma unroll
        for (int i = 0; i < 64; ++i) ukz[i] = u0[i << 8];
        const unsigned int* u1 = u0 + (128 << 8);
#pragma unroll
        for (int i = 0; i < 64; ++i) ukr[i] = u1[i << 8];
        const unsigned int* u2 = u1 + (128 << 8);
#pragma unroll
        for (int i = 0; i < 64; ++i) ukh[i] = u2[i << 8];
    }
#pragma unroll
    for (int i = 0; i < 64; ++i) {
        asm volatile("" : "+v"(ukz[i]), "+v"(ukr[i]), "+v"(ukh[i]));
    }

    int S = len[b] - t0;
    S = S < 0 ? 0 : (S > CT ? CT : S);

    float hprev = 0.f, bz = 0.f, br = 0.f, bh = 0.f;
    if (tid < 256) {
        hprev = (t0 == 0) ? 0.f : out[(size_t)b * Uu + col];
        bz = bias1[col];
        br = bias1[col + 256];
        bh = bias1[col + 512];
    }
    if (tid < 128) {
        float e0 = 0.f, e1 = 0.f;
        if (t0 != 0) {
            e0 = out[(size_t)b * Uu + 2 * tid];
            e1 = out[(size_t)b * Uu + 2 * tid + 1];
        }
        hH[tid] = pack2(e0, e1);
    }
    __syncthreads();

    const unsigned char* mrow_mask = mask + (size_t)b * Tt + t0;
    for (int s = 0; s < S; ++s) {
        float mxz = 0.f, mxr = 0.f, mxh = 0.f;
        unsigned char m = 0;
        if (tid < 256) {
            const float* mrow = matx + ((size_t)b * CT + s) * NJ;
            mxz = mrow[col];
            mxr = mrow[col + 256];
            mxh = mrow[col + 512];
            m = mrow_mask[s];
        }

        float az = 0.f, ar = 0.f, ah = 0.f;
        const unsigned int* hp = &hH[khalf << 6];
#pragma unroll
        for (int i = 0; i < 16; ++i) {
            uint4 q = *reinterpret_cast<const uint4*>(hp + (i << 2));
            az = dot2_acc(ukz[4 * i + 0], q.x, az);
            ar = dot2_acc(ukr[4 * i + 0], q.x, ar);
            ah = dot2_acc(ukh[4 * i + 0], q.x, ah);
            az = dot2_acc(ukz[4 * i + 1], q.y, az);
            ar = dot2_acc(ukr[4 * i + 1], q.y, ar);
            ah = dot2_acc(ukh[4 * i + 1], q.y, ah);
            az = dot2_acc(ukz[4 * i + 2], q.z, az);
            ar = dot2_acc(ukr[4 * i + 2], q.z, ar);
            ah = dot2_acc(ukh[4 * i + 2], q.z, ah);
            az = dot2_acc(ukz[4 * i + 3], q.w, az);
            ar = dot2_acc(ukr[4 * i + 3], q.w, ar);
            ah = dot2_acc(ukh[4 * i + 3], q.w, ah);
        }
        part[khalf][0][col] = az;
        part[khalf][1][col] = ar;
        part[khalf][2][col] = ah;
        __syncthreads();

        if (tid < 256) {
            float azs = part[0][0][col] + part[1][0][col];
            float ars = part[0][1][col] + part[1][1][col];
            float ahs = part[0][2][col] + part[1][2][col];
            float hn = hprev;
            if (m) {
                float z = 1.f / (1.f + expf(-(mxz + azs + bz)));
                float r = 1.f / (1.f + expf(-(mxr + ars + br)));
                float hc = tanhf(mxh + r * (ahs + bh));
                hn = z * hprev + (1.f - z) * hc;
            }
            hprev = hn;
            float ho = __shfl_xor(hn, 1);
            if (!(col & 1)) hH[col >> 1] = pack2(hn, ho);
        }
        __syncthreads();
    }

    if (tid < 256) out[(size_t)b * Uu + col] = hprev;
}

// ---------------------------------------------------------------- launcher
extern "C" void kernel_launch(void* const* d_in, const int* in_sizes, int n_in,
                              void* d_out, int out_size, void* d_ws, size_t ws_size,
                              hipStream_t stream) {
    const float* codes = (const float*)d_in[0];
    const float* W     = (const float*)d_in[1];
    const float* Uk    = (const float*)d_in[2];
    const float* bias  = (const float*)d_in[3];   // [2][768]
    float* out = (float*)d_out;

    char* ws = (char*)d_ws;
    int* len = (int*)ws;
    unsigned char* mask = (unsigned char*)(ws + WS_MASK);
    unsigned int* ukp = (unsigned int*)(ws + WS_UKP);
    float* matx = (float*)(ws + WS_MATX);

    int CT = 1;
    for (int cc = 512; cc >= 1; cc >>= 1) {
        if ((size_t)WS_MATX + (size_t)cc * 786432ull <= ws_size) { CT = cc; break; }
    }
    int ctShift = __builtin_ctz((unsigned)CT);
    int nch = 512 / CT;

    zero_len_kernel<<<1, 256, 0, stream>>>(len);
    mask_len_kernel<<<Bb * Tt / 4, 256, 0, stream>>>(codes, mask, len);
    uk_convert_kernel<<<384, 256, 0, stream>>>(Uk, ukp);

    for (int c = 0; c < nch; ++c) {
        int t0 = c * CT;
        dim3 grid(2 * CT, 6);  // (256*CT/128, 768/128)
        matx_gemm_mfma<<<grid, 256, 0, stream>>>(codes, W, bias, matx, t0, ctShift);
        gru_scan_kernel<<<Bb, 512, 0, stream>>>(matx, ukp, bias + NJ, mask, len,
                                                out, t0, CT);
    }
}

// Round 5
// 1415.889 us; speedup vs baseline: 5.1682x; 1.0212x over previous
//
#include <hip/hip_runtime.h>
#include <hip/hip_bf16.h>
#include <cstdint>
#include <cstddef>

#define Bb 256
#define Tt 512
#define Dd 256
#define Uu 256
#define NJ 768  // 3*U

// ws layout (bytes):
//   len  @ 0         : 1024
//   mask @ 1024      : 131072
//   ukp  @ 132096    : 3*128*256 uint  = 393216   (packed fp16 Uk pairs)
//   WH   @ 525312    : 256*768 ushort  = 393216   (bf16-hi W, fragment layout)
//   WL   @ 918528    : 393216                      (bf16-lo W)
//   CH   @ 1311744   : 131072*256 ush  = 67108864  (bf16-hi codes, fragment layout)
//   CL   @ 68420608  : 67108864
//   matx @ 135529472 : B * CT * 768 f32
#define WS_MASK  1024
#define WS_UKP   132096
#define WS_WH    525312
#define WS_WL    918528
#define WS_CH    1311744
#define WS_CL    68420608
#define WS_MATX  135529472ull

typedef _Float16 h2 __attribute__((ext_vector_type(2)));
typedef short short8 __attribute__((ext_vector_type(8)));
typedef float f32x4 __attribute__((ext_vector_type(4)));

#if defined(__has_builtin)
#if __has_builtin(__builtin_amdgcn_fdot2)
#define HAVE_FDOT2 1
#endif
#endif

__device__ __forceinline__ unsigned int pack2(float a, float b) {
    h2 v;
    v.x = (_Float16)a;
    v.y = (_Float16)b;
    return __builtin_bit_cast(unsigned int, v);
}

__device__ __forceinline__ float dot2_acc(unsigned int u, unsigned int hv, float acc) {
    h2 a = __builtin_bit_cast(h2, u);
    h2 b = __builtin_bit_cast(h2, hv);
#ifdef HAVE_FDOT2
    return __builtin_amdgcn_fdot2(a, b, acc, false);
#else
    return acc + (float)a.x * (float)b.x + (float)a.y * (float)b.y;
#endif
}

// truncation split: x = hi + lo + O(2^-16 |x|)
__device__ __forceinline__ void bfsplit(float x, unsigned short& h, unsigned short& l) {
    unsigned u = __builtin_bit_cast(unsigned, x);
    h = (unsigned short)(u >> 16);
    float hf = __builtin_bit_cast(float, u & 0xFFFF0000u);
    float lf = x - hf;  // exact
    l = (unsigned short)(__builtin_bit_cast(unsigned, lf) >> 16);
}

union PK8 { unsigned short s[8]; uint4 v; };

// ---------------------------------------------------------------- utilities
__global__ void zero_len_kernel(int* __restrict__ len) {
    if (threadIdx.x < Bb) len[threadIdx.x] = 0;
}

// one wave per (b,t) row; 4 rows per 256-thread block; grid = B*T/4
__global__ void mask_len_kernel(const float* __restrict__ codes,
                                unsigned char* __restrict__ mask,
                                int* __restrict__ len) {
    const int wave = threadIdx.x >> 6;
    const int lane = threadIdx.x & 63;
    const long long row = (long long)blockIdx.x * 4 + wave;  // b*T + t
    const float4* p = reinterpret_cast<const float4*>(codes + row * Dd);
    float4 v = p[lane];
    bool nz = (v.x != 0.f) || (v.y != 0.f) || (v.z != 0.f) || (v.w != 0.f);
    unsigned long long ball = __ballot(nz);
    if (lane == 0) {
        int b = (int)(row >> 9);
        int t = (int)(row & 511);
        unsigned char m = (ball != 0ull) ? 1 : 0;
        mask[row] = m;
        if (m) atomicMax(&len[b], t + 1);
    }
}

// Uk fp32 [256][768] -> packed fp16 pairs ukp[g][kp][col]
__global__ void uk_convert_kernel(const float* __restrict__ Uk,
                                  unsigned int* __restrict__ ukp) {
    int idx = blockIdx.x * 256 + threadIdx.x;  // 0..98303
    int col = idx & 255;
    int kp = (idx >> 8) & 127;
    int g = idx >> 15;
    float a = Uk[(size_t)(2 * kp) * NJ + (g << 8) + col];
    float b = Uk[(size_t)(2 * kp + 1) * NJ + (g << 8) + col];
    ukp[idx] = pack2(a, b);
}

// W [256k][768n] fp32 -> WH/WL bf16 in MFMA-B-fragment layout.
// uint4 index T: lane=T&63, nsub=(T>>6)&7, ki=(T>>9)&7, cs=T>>12.
// Fragment: lane holds col = cs*128+nsub*16+(lane&15), k = ki*32+((lane>>4)&3)*8+e.
__global__ void wsplit_kernel(const float* __restrict__ W,
                              uint4* __restrict__ WH4, uint4* __restrict__ WL4) {
    int T = blockIdx.x * 256 + threadIdx.x;  // 0..24575
    int lane = T & 63, nsub = (T >> 6) & 7, ki = (T >> 9) & 7, cs = T >> 12;
    int n = cs * 128 + nsub * 16 + (lane & 15);
    int k0 = ki * 32 + ((lane >> 4) & 3) * 8;
    PK8 hp, lp;
#pragma unroll
    for (int e = 0; e < 8; ++e) bfsplit(W[(size_t)(k0 + e) * NJ + n], hp.s[e], lp.s[e]);
    WH4[T] = hp.v;
    WL4[T] = lp.v;
}

// codes [131072r][256k] fp32 -> CH/CL bf16 in MFMA-A-fragment layout.
// uint4 index T: lane=T&63, rsub=(T>>6)&7, ki=(T>>9)&7, tile=T>>12 (0..1023).
// Fragment: lane holds row = tile*128+rsub*16+(lane&15), k = ki*32+((lane>>4)&3)*8+e.
__global__ void csplit_kernel(const float* __restrict__ codes,
                              uint4* __restrict__ CH4, uint4* __restrict__ CL4) {
    int T = blockIdx.x * 256 + threadIdx.x;  // 0..4194303
    int lane = T & 63, rsub = (T >> 6) & 7, ki = (T >> 9) & 7, tile = T >> 12;
    size_t row = (size_t)tile * 128 + rsub * 16 + (lane & 15);
    int k0 = ki * 32 + ((lane >> 4) & 3) * 8;
    const float* cp = codes + row * Dd + k0;
    float4 f0 = *reinterpret_cast<const float4*>(cp);
    float4 f1 = *reinterpret_cast<const float4*>(cp + 4);
    float e[8] = {f0.x, f0.y, f0.z, f0.w, f1.x, f1.y, f1.z, f1.w};
    PK8 hp, lp;
#pragma unroll
    for (int i = 0; i < 8; ++i) bfsplit(e[i], hp.s[i], lp.s[i]);
    CH4[T] = hp.v;
    CL4[T] = lp.v;
}

// ------------------------------------------------- phase 1: mat_x = codes@W + b0
// Pure-register bf16-split MFMA GEMM (no LDS, no barriers): fragments loaded
// coalesced from pre-split CH/CL/WH/WL, double-buffered across the 8 ki-blocks.
// C = ah@bh + ah@bl + al@bh (fp32 acc). Wave w owns quadrant ((w&1),(w>>1)).
#define LOADF(buf, kig)                                                        \
    do {                                                                       \
        _Pragma("unroll") for (int x = 0; x < 4; ++x) {                        \
            ah[buf][x] = Ahp[(kig) * 512 + x * 64];                            \
            al[buf][x] = Alp[(kig) * 512 + x * 64];                            \
            bh[buf][x] = Bhp[(kig) * 512 + x * 64];                            \
            bl[buf][x] = Blp[(kig) * 512 + x * 64];                            \
        }                                                                      \
    } while (0)

__global__ __launch_bounds__(256, 2)
void matx_gemm_reg(const uint4* __restrict__ CH4, const uint4* __restrict__ CL4,
                   const uint4* __restrict__ WH4, const uint4* __restrict__ WL4,
                   const float* __restrict__ b0, float* __restrict__ matx,
                   int t0, int ctShift) {
    const int tid = threadIdx.x;
    const int w = tid >> 6, lane = tid & 63;
    const int mbase = (w & 1) * 4, nbase = (w >> 1) * 4;
    const int cs = blockIdx.y;
    const int rbase = blockIdx.x * 128;
    // global codes-row tile (CT >= 128 guarantees 128 consecutive aligned rows)
    const int ctMask = (1 << ctShift) - 1;
    const size_t grow0 = (size_t)(rbase >> ctShift) * Tt + (size_t)(t0 + (rbase & ctMask));
    const size_t gtile = grow0 >> 7;

    const uint4* Ahp = CH4 + gtile * 4096 + mbase * 64 + lane;
    const uint4* Alp = CL4 + gtile * 4096 + mbase * 64 + lane;
    const uint4* Bhp = WH4 + (size_t)cs * 4096 + nbase * 64 + lane;
    const uint4* Blp = WL4 + (size_t)cs * 4096 + nbase * 64 + lane;

    f32x4 acc[4][4];
#pragma unroll
    for (int i = 0; i < 4; ++i)
#pragma unroll
        for (int j = 0; j < 4; ++j) acc[i][j] = (f32x4){0.f, 0.f, 0.f, 0.f};

    uint4 ah[2][4], al[2][4], bh[2][4], bl[2][4];
    LOADF(0, 0);
#pragma unroll
    for (int kig = 0; kig < 8; ++kig) {
        const int cur = kig & 1, nx = cur ^ 1;
        if (kig < 7) LOADF(nx, kig + 1);
#pragma unroll
        for (int mi = 0; mi < 4; ++mi) {
            short8 am = __builtin_bit_cast(short8, ah[cur][mi]);
            short8 al8 = __builtin_bit_cast(short8, al[cur][mi]);
#pragma unroll
            for (int ni = 0; ni < 4; ++ni) {
                short8 bn = __builtin_bit_cast(short8, bh[cur][ni]);
                short8 bl8 = __builtin_bit_cast(short8, bl[cur][ni]);
                acc[mi][ni] = __builtin_amdgcn_mfma_f32_16x16x32_bf16(am, bn, acc[mi][ni], 0, 0, 0);
                acc[mi][ni] = __builtin_amdgcn_mfma_f32_16x16x32_bf16(am, bl8, acc[mi][ni], 0, 0, 0);
                acc[mi][ni] = __builtin_amdgcn_mfma_f32_16x16x32_bf16(al8, bn, acc[mi][ni], 0, 0, 0);
            }
        }
    }
    // epilogue: C/D layout col=lane&15, row=(lane>>4)*4+reg (HW-verified r4)
    const int colq = lane & 15, rowq = (lane >> 4) * 4;
    const int cbase = cs * 128;
#pragma unroll
    for (int ni = 0; ni < 4; ++ni) {
        int cc = cbase + (w >> 1) * 64 + ni * 16 + colq;
        float bv = b0[cc];
#pragma unroll
        for (int mi = 0; mi < 4; ++mi) {
            int gr = rbase + (w & 1) * 64 + mi * 16 + rowq;
#pragma unroll
            for (int j = 0; j < 4; ++j)
                matx[(size_t)(gr + j) * NJ + cc] = acc[mi][ni][j] + bv;
        }
    }
}

// ------------------------------------------------- phase 2: sequential GRU scan
// One 512-thread block per batch row; no inter-block sync. Thread (col, khalf)
// holds 192 packed-fp16 Uk uints. Pin chain is INSIDE the step loop: iteration
// s+1's pin input is iteration s's pin output, so the compiler cannot
// rematerialize the global loads (rounds 2-4 failure mode).
__global__ __launch_bounds__(512, 2)
void gru_scan_kernel(const float* __restrict__ matx,
                     const unsigned int* __restrict__ ukp,
                     const float* __restrict__ bias1,
                     const unsigned char* __restrict__ mask,
                     const int* __restrict__ len,
                     float* __restrict__ out,
                     int t0, int CT) {
    __shared__ __align__(16) unsigned int hH[128];  // packed fp16 h pairs
    __shared__ float part[2][3][Uu];                // [khalf][gate][col]

    const int tid = threadIdx.x;
    const int b = blockIdx.x;
    const int col = tid & 255;
    const int khalf = tid >> 8;

    unsigned int ukz[64], ukr[64], ukh[64];
    {
        const unsigned int* u0 = ukp + (khalf << 14) + col;
#pragma unroll
        for (int i = 0; i < 64; ++i) ukz[i] = u0[i << 8];
        const unsigned int* u1 = u0 + (128 << 8);
#pragma unroll
        for (int i = 0; i < 64; ++i) ukr[i] = u1[i << 8];
        const unsigned int* u2 = u1 + (128 << 8);
#pragma unroll
        for (int i = 0; i < 64; ++i) ukh[i] = u2[i << 8];
    }

    int S = len[b] - t0;
    S = S < 0 ? 0 : (S > CT ? CT : S);

    float hprev = 0.f, bz = 0.f, br = 0.f, bh = 0.f;
    if (tid < 256) {
        hprev = (t0 == 0) ? 0.f : out[(size_t)b * Uu + col];
        bz = bias1[col];
        br = bias1[col + 256];
        bh = bias1[col + 512];
    }
    if (tid < 128) {
        float e0 = 0.f, e1 = 0.f;
        if (t0 != 0) {
            e0 = out[(size_t)b * Uu + 2 * tid];
            e1 = out[(size_t)b * Uu + 2 * tid + 1];
        }
        hH[tid] = pack2(e0, e1);
    }
    __syncthreads();

    const unsigned char* mrow_mask = mask + (size_t)b * Tt + t0;
    for (int s = 0; s < S; ++s) {
        // pin chain: forces all 192 Uk values to stay register-resident
#pragma unroll
        for (int i = 0; i < 64; ++i) {
            asm volatile("" : "+v"(ukz[i]), "+v"(ukr[i]), "+v"(ukh[i]));
        }
        float mxz = 0.f, mxr = 0.f, mxh = 0.f;
        unsigned char m = 0;
        if (tid < 256) {
            const float* mrow = matx + ((size_t)b * CT + s) * NJ;
            mxz = mrow[col];
            mxr = mrow[col + 256];
            mxh = mrow[col + 512];
            m = mrow_mask[s];
        }

        float az = 0.f, ar = 0.f, ah = 0.f;
        const unsigned int* hp = &hH[khalf << 6];
#pragma unroll
        for (int i = 0; i < 16; ++i) {
            uint4 q = *reinterpret_cast<const uint4*>(hp + (i << 2));
            az = dot2_acc(ukz[4 * i + 0], q.x, az);
            ar = dot2_acc(ukr[4 * i + 0], q.x, ar);
            ah = dot2_acc(ukh[4 * i + 0], q.x, ah);
            az = dot2_acc(ukz[4 * i + 1], q.y, az);
            ar = dot2_acc(ukr[4 * i + 1], q.y, ar);
            ah = dot2_acc(ukh[4 * i + 1], q.y, ah);
            az = dot2_acc(ukz[4 * i + 2], q.z, az);
            ar = dot2_acc(ukr[4 * i + 2], q.z, ar);
            ah = dot2_acc(ukh[4 * i + 2], q.z, ah);
            az = dot2_acc(ukz[4 * i + 3], q.w, az);
            ar = dot2_acc(ukr[4 * i + 3], q.w, ar);
            ah = dot2_acc(ukh[4 * i + 3], q.w, ah);
        }
        part[khalf][0][col] = az;
        part[khalf][1][col] = ar;
        part[khalf][2][col] = ah;
        __syncthreads();

        if (tid < 256) {
            float azs = part[0][0][col] + part[1][0][col];
            float ars = part[0][1][col] + part[1][1][col];
            float ahs = part[0][2][col] + part[1][2][col];
            float hn = hprev;
            if (m) {
                float z = 1.f / (1.f + expf(-(mxz + azs + bz)));
                float r = 1.f / (1.f + expf(-(mxr + ars + br)));
                float hc = tanhf(mxh + r * (ahs + bh));
                hn = z * hprev + (1.f - z) * hc;
            }
            hprev = hn;
            float ho = __shfl_xor(hn, 1);
            if (!(col & 1)) hH[col >> 1] = pack2(hn, ho);
        }
        __syncthreads();
    }

    if (tid < 256) out[(size_t)b * Uu + col] = hprev;
}

// ---------------------------------------------------------------- launcher
extern "C" void kernel_launch(void* const* d_in, const int* in_sizes, int n_in,
                              void* d_out, int out_size, void* d_ws, size_t ws_size,
                              hipStream_t stream) {
    const float* codes = (const float*)d_in[0];
    const float* W     = (const float*)d_in[1];
    const float* Uk    = (const float*)d_in[2];
    const float* bias  = (const float*)d_in[3];   // [2][768]
    float* out = (float*)d_out;

    char* ws = (char*)d_ws;
    int* len = (int*)ws;
    unsigned char* mask = (unsigned char*)(ws + WS_MASK);
    unsigned int* ukp = (unsigned int*)(ws + WS_UKP);
    uint4* WH4 = (uint4*)(ws + WS_WH);
    uint4* WL4 = (uint4*)(ws + WS_WL);
    uint4* CH4 = (uint4*)(ws + WS_CH);
    uint4* CL4 = (uint4*)(ws + WS_CL);
    float* matx = (float*)(ws + WS_MATX);

    // time-chunk: smallest count with CT >= 128 (fragment tiles need 128
    // consecutive aligned rows); observed ws_size comfortably fits CT=256+.
    int CT = 128;
    for (int cc = 512; cc >= 128; cc >>= 1) {
        if (WS_MATX + (size_t)cc * 786432ull <= ws_size) { CT = cc; break; }
    }
    int ctShift = __builtin_ctz((unsigned)CT);
    int nch = 512 / CT;

    zero_len_kernel<<<1, 256, 0, stream>>>(len);
    mask_len_kernel<<<Bb * Tt / 4, 256, 0, stream>>>(codes, mask, len);
    uk_convert_kernel<<<384, 256, 0, stream>>>(Uk, ukp);
    wsplit_kernel<<<96, 256, 0, stream>>>(W, WH4, WL4);
    csplit_kernel<<<16384, 256, 0, stream>>>(codes, CH4, CL4);

    for (int c = 0; c < nch; ++c) {
        int t0 = c * CT;
        dim3 grid(2 * CT, 6);  // (256*CT/128, 768/128)
        matx_gemm_reg<<<grid, 256, 0, stream>>>(CH4, CL4, WH4, WL4, bias, matx,
                                                t0, ctShift);
        gru_scan_kernel<<<Bb, 512, 0, stream>>>(matx, ukp, bias + NJ, mask, len,
                                                out, t0, CT);
    }
}

// Round 8
// 1374.897 us; speedup vs baseline: 5.3223x; 1.0298x over previous
//
#include <hip/hip_runtime.h>
#include <hip/hip_bf16.h>
#include <cstdint>
#include <cstddef>

#define Bb 256
#define Tt 512
#define Dd 256
#define Uu 256
#define NJ 768  // 3*U

// ws layout (bytes):
//   len  @ 0        : 1024
//   mask @ 1024     : 131072
//   ukp  @ 132096   : 3*128*256 uint = 393216  (packed fp16 Uk pairs)
//   WH   @ 525312   : 256*768 ushort = 393216  (bf16-hi W, fragment layout)
//   WL   @ 918528   : 393216                    (bf16-lo W)
//   matx @ 1311744  : B * CT * 768 _Float16
#define WS_MASK  1024
#define WS_UKP   132096
#define WS_WH    525312
#define WS_WL    918528
#define WS_MATX  1311744ull

typedef _Float16 h2 __attribute__((ext_vector_type(2)));
typedef short short8 __attribute__((ext_vector_type(8)));
typedef float f32x4 __attribute__((ext_vector_type(4)));

#if defined(__has_builtin)
#if __has_builtin(__builtin_amdgcn_fdot2)
#define HAVE_FDOT2 1
#endif
#endif

__device__ __forceinline__ unsigned int pack2(float a, float b) {
    h2 v;
    v.x = (_Float16)a;
    v.y = (_Float16)b;
    return __builtin_bit_cast(unsigned int, v);
}

__device__ __forceinline__ float dot2_acc(unsigned int u, unsigned int hv, float acc) {
    h2 a = __builtin_bit_cast(h2, u);
    h2 b = __builtin_bit_cast(h2, hv);
#ifdef HAVE_FDOT2
    return __builtin_amdgcn_fdot2(a, b, acc, false);
#else
    return acc + (float)a.x * (float)b.x + (float)a.y * (float)b.y;
#endif
}

// truncation split: x = hi + lo + O(2^-16 |x|)
__device__ __forceinline__ void bfsplit(float x, unsigned short& h, unsigned short& l) {
    unsigned u = __builtin_bit_cast(unsigned, x);
    h = (unsigned short)(u >> 16);
    float hf = __builtin_bit_cast(float, u & 0xFFFF0000u);
    float lf = x - hf;  // exact
    l = (unsigned short)(__builtin_bit_cast(unsigned, lf) >> 16);
}

union PK8 { unsigned short s[8]; uint4 v; };

// ---------------------------------------------------------------- utilities
__global__ void zero_len_kernel(int* __restrict__ len) {
    if (threadIdx.x < Bb) len[threadIdx.x] = 0;
}

// one wave per (b,t) row; 4 rows per 256-thread block; grid = B*T/4
__global__ void mask_len_kernel(const float* __restrict__ codes,
                                unsigned char* __restrict__ mask,
                                int* __restrict__ len) {
    const int wave = threadIdx.x >> 6;
    const int lane = threadIdx.x & 63;
    const long long row = (long long)blockIdx.x * 4 + wave;  // b*T + t
    const float4* p = reinterpret_cast<const float4*>(codes + row * Dd);
    float4 v = p[lane];
    bool nz = (v.x != 0.f) || (v.y != 0.f) || (v.z != 0.f) || (v.w != 0.f);
    unsigned long long ball = __ballot(nz);
    if (lane == 0) {
        int b = (int)(row >> 9);
        int t = (int)(row & 511);
        unsigned char m = (ball != 0ull) ? 1 : 0;
        mask[row] = m;
        if (m) atomicMax(&len[b], t + 1);
    }
}

// Uk fp32 [256][768] -> packed fp16 pairs ukp[g][kp][col]
__global__ void uk_convert_kernel(const float* __restrict__ Uk,
                                  unsigned int* __restrict__ ukp) {
    int idx = blockIdx.x * 256 + threadIdx.x;  // 0..98303
    int col = idx & 255;
    int kp = (idx >> 8) & 127;
    int g = idx >> 15;
    float a = Uk[(size_t)(2 * kp) * NJ + (g << 8) + col];
    float b = Uk[(size_t)(2 * kp + 1) * NJ + (g << 8) + col];
    ukp[idx] = pack2(a, b);
}

// W [256k][768n] fp32 -> WH/WL bf16 in MFMA-B-fragment layout.
// uint4 index T: lane=T&63, nsub=(T>>6)&7, ki=(T>>9)&7, cs=T>>12.
// Fragment: lane holds col = cs*128+nsub*16+(lane&15), k = ki*32+((lane>>4)&3)*8+e.
__global__ void wsplit_kernel(const float* __restrict__ W,
                              uint4* __restrict__ WH4, uint4* __restrict__ WL4) {
    int T = blockIdx.x * 256 + threadIdx.x;  // 0..24575
    int lane = T & 63, nsub = (T >> 6) & 7, ki = (T >> 9) & 7, cs = T >> 12;
    int n = cs * 128 + nsub * 16 + (lane & 15);
    int k0 = ki * 32 + ((lane >> 4) & 3) * 8;
    PK8 hp, lp;
#pragma unroll
    for (int e = 0; e < 8; ++e) bfsplit(W[(size_t)(k0 + e) * NJ + n], hp.s[e], lp.s[e]);
    WH4[T] = hp.v;
    WL4[T] = lp.v;
}

// ------------------------------------------------- phase 1: mat_x = codes@W + b0
// bf16-split MFMA GEMM, fp16 output. A staged from raw codes via LDS (float4
// coalesced, in-kernel split, fragment-layout writes — r4-verified indexing).
// B fragments register-loaded from pre-split WH/WL (131 KB/strip, L2-hot),
// prefetched before the staging barrier. C = ah@bh + ah@bl + al@bh.
__global__ __launch_bounds__(256, 2)
void matx_gemm_half(const float* __restrict__ codes,
                    const uint4* __restrict__ WH4, const uint4* __restrict__ WL4,
                    const float* __restrict__ b0, _Float16* __restrict__ matx,
                    int t0, int ctShift) {
    __shared__ uint4 AH[1024], AL[1024];  // 16 KB each
    const int tid = threadIdx.x;
    const int w = tid >> 6, lane = tid & 63;
    const int rbase = blockIdx.x * 128;
    const int cs = blockIdx.y;
    const int ctMask = (1 << ctShift) - 1;
    const int mbase = (w & 1) * 4, nbase = (w >> 1) * 4;

    f32x4 acc[4][4];
#pragma unroll
    for (int i = 0; i < 4; ++i)
#pragma unroll
        for (int j = 0; j < 4; ++j) acc[i][j] = (f32x4){0.f, 0.f, 0.f, 0.f};

    const uint4* Bh0 = WH4 + (size_t)cs * 4096 + nbase * 64 + lane;
    const uint4* Bl0 = WL4 + (size_t)cs * 4096 + nbase * 64 + lane;

    for (int kt = 0; kt < 4; ++kt) {
        const int k0 = kt * 64;
        // prefetch this kt's B fragments (2 ki-halves x 4 n-frags, hi+lo)
        uint4 bhv[2][4], blv[2][4];
#pragma unroll
        for (int ki2 = 0; ki2 < 2; ++ki2)
#pragma unroll
            for (int x = 0; x < 4; ++x) {
                bhv[ki2][x] = Bh0[(kt * 2 + ki2) * 512 + x * 64];
                blv[ki2][x] = Bl0[(kt * 2 + ki2) * 512 + x * 64];
            }
        // stage A (128 rows x 64 k), fp32 -> bf16 hi/lo, fragment layout
        if (kt > 0) __syncthreads();  // protect LDS reuse from prior reads
#pragma unroll
        for (int u = 0; u < 4; ++u) {
            int L = u * 256 + tid;
            int r = L >> 3, o = L & 7;  // row in tile, k-octet
            int gr = rbase + r;
            size_t g = (size_t)(gr >> ctShift) * Tt + (size_t)(t0 + (gr & ctMask));
            const float* cp = codes + g * Dd + k0 + (o << 3);
            float4 f0 = *reinterpret_cast<const float4*>(cp);
            float4 f1 = *reinterpret_cast<const float4*>(cp + 4);
            float e[8] = {f0.x, f0.y, f0.z, f0.w, f1.x, f1.y, f1.z, f1.w};
            PK8 hp, lp;
#pragma unroll
            for (int i = 0; i < 8; ++i) bfsplit(e[i], hp.s[i], lp.s[i]);
            int idx = (((o >> 2) * 8 + (r >> 4)) << 6) + ((r & 15) | ((o & 3) << 4));
            AH[idx] = hp.v;
            AL[idx] = lp.v;
        }
        __syncthreads();
#pragma unroll
        for (int ki2 = 0; ki2 < 2; ++ki2) {
            short8 ah[4], al8[4];
#pragma unroll
            for (int x = 0; x < 4; ++x) {
                ah[x]  = *reinterpret_cast<const short8*>(&AH[((ki2 * 8 + mbase + x) << 6) + lane]);
                al8[x] = *reinterpret_cast<const short8*>(&AL[((ki2 * 8 + mbase + x) << 6) + lane]);
            }
#pragma unroll
            for (int mi = 0; mi < 4; ++mi)
#pragma unroll
                for (int ni = 0; ni < 4; ++ni) {
                    short8 bn  = __builtin_bit_cast(short8, bhv[ki2][ni]);
                    short8 bl8 = __builtin_bit_cast(short8, blv[ki2][ni]);
                    acc[mi][ni] = __builtin_amdgcn_mfma_f32_16x16x32_bf16(ah[mi], bn, acc[mi][ni], 0, 0, 0);
                    acc[mi][ni] = __builtin_amdgcn_mfma_f32_16x16x32_bf16(ah[mi], bl8, acc[mi][ni], 0, 0, 0);
                    acc[mi][ni] = __builtin_amdgcn_mfma_f32_16x16x32_bf16(al8[mi], bn, acc[mi][ni], 0, 0, 0);
                }
        }
    }
    // epilogue: C/D layout col=lane&15, row=(lane>>4)*4+reg (HW-verified r4/r5)
    const int colq = lane & 15, rowq = (lane >> 4) * 4;
    const int cbase = cs * 128;
#pragma unroll
    for (int ni = 0; ni < 4; ++ni) {
        int cc = cbase + (w >> 1) * 64 + ni * 16 + colq;
        float bv = b0[cc];
#pragma unroll
        for (int mi = 0; mi < 4; ++mi) {
            int gr = rbase + (w & 1) * 64 + mi * 16 + rowq;
#pragma unroll
            for (int j = 0; j < 4; ++j)
                matx[(size_t)(gr + j) * NJ + cc] = (_Float16)(acc[mi][ni][j] + bv);
        }
    }
}

// ------------------------------------------------- phase 2: sequential GRU scan
// One 512-thread block per batch row; no inter-block sync. Thread (col, khalf)
// holds 192 packed-fp16 Uk uints, pinned register/AGPR-resident via the
// in-step-loop asm chain (r5-verified: 745 -> 406 us). matx read as fp16.
__global__ __launch_bounds__(512, 2)
void gru_scan_kernel(const _Float16* __restrict__ matx,
                     const unsigned int* __restrict__ ukp,
                     const float* __restrict__ bias1,
                     const unsigned char* __restrict__ mask,
                     const int* __restrict__ len,
                     float* __restrict__ out,
                     int t0, int CT) {
    __shared__ __align__(16) unsigned int hH[128];  // packed fp16 h pairs
    __shared__ float part[2][3][Uu];                // [khalf][gate][col]

    const int tid = threadIdx.x;
    const int b = blockIdx.x;
    const int col = tid & 255;
    const int khalf = tid >> 8;

    unsigned int ukz[64], ukr[64], ukh[64];
    {
        const unsigned int* u0 = ukp + (khalf << 14) + col;
#pragma unroll
        for (int i = 0; i < 64; ++i) ukz[i] = u0[i << 8];
        const unsigned int* u1 = u0 + (128 << 8);
#pragma unroll
        for (int i = 0; i < 64; ++i) ukr[i] = u1[i << 8];
        const unsigned int* u2 = u1 + (128 << 8);
#pragma unroll
        for (int i = 0; i < 64; ++i) ukh[i] = u2[i << 8];
    }

    int S = len[b] - t0;
    S = S < 0 ? 0 : (S > CT ? CT : S);

    float hprev = 0.f, bz = 0.f, br = 0.f, bh = 0.f;
    if (tid < 256) {
        hprev = (t0 == 0) ? 0.f : out[(size_t)b * Uu + col];
        bz = bias1[col];
        br = bias1[col + 256];
        bh = bias1[col + 512];
    }
    if (tid < 128) {
        float e0 = 0.f, e1 = 0.f;
        if (t0 != 0) {
            e0 = out[(size_t)b * Uu + 2 * tid];
            e1 = out[(size_t)b * Uu + 2 * tid + 1];
        }
        hH[tid] = pack2(e0, e1);
    }
    __syncthreads();

    const unsigned char* mrow_mask = mask + (size_t)b * Tt + t0;
    for (int s = 0; s < S; ++s) {
        // pin chain: forces the 192 Uk values loop-carried register-resident
#pragma unroll
        for (int i = 0; i < 64; ++i) {
            asm volatile("" : "+v"(ukz[i]), "+v"(ukr[i]), "+v"(ukh[i]));
        }
        float mxz = 0.f, mxr = 0.f, mxh = 0.f;
        unsigned char m = 0;
        if (tid < 256) {
            const _Float16* mrow = matx + ((size_t)b * CT + s) * NJ;
            mxz = (float)mrow[col];
            mxr = (float)mrow[col + 256];
            mxh = (float)mrow[col + 512];
            m = mrow_mask[s];
        }

        float az = 0.f, ar = 0.f, ah = 0.f;
        const unsigned int* hp = &hH[khalf << 6];
#pragma unroll
        for (int i = 0; i < 16; ++i) {
            uint4 q = *reinterpret_cast<const uint4*>(hp + (i << 2));
            az = dot2_acc(ukz[4 * i + 0], q.x, az);
            ar = dot2_acc(ukr[4 * i + 0], q.x, ar);
            ah = dot2_acc(ukh[4 * i + 0], q.x, ah);
            az = dot2_acc(ukz[4 * i + 1], q.y, az);
            ar = dot2_acc(ukr[4 * i + 1], q.y, ar);
            ah = dot2_acc(ukh[4 * i + 1], q.y, ah);
            az = dot2_acc(ukz[4 * i + 2], q.z, az);
            ar = dot2_acc(ukr[4 * i + 2], q.z, ar);
            ah = dot2_acc(ukh[4 * i + 2], q.z, ah);
            az = dot2_acc(ukz[4 * i + 3], q.w, az);
            ar = dot2_acc(ukr[4 * i + 3], q.w, ar);
            ah = dot2_acc(ukh[4 * i + 3], q.w, ah);
        }
        part[khalf][0][col] = az;
        part[khalf][1][col] = ar;
        part[khalf][2][col] = ah;
        __syncthreads();

        if (tid < 256) {
            float azs = part[0][0][col] + part[1][0][col];
            float ars = part[0][1][col] + part[1][1][col];
            float ahs = part[0][2][col] + part[1][2][col];
            float hn = hprev;
            if (m) {
                float z = 1.f / (1.f + expf(-(mxz + azs + bz)));
                float r = 1.f / (1.f + expf(-(mxr + ars + br)));
                float hc = tanhf(mxh + r * (ahs + bh));
                hn = z * hprev + (1.f - z) * hc;
            }
            hprev = hn;
            float ho = __shfl_xor(hn, 1);
            if (!(col & 1)) hH[col >> 1] = pack2(hn, ho);
        }
        __syncthreads();
    }

    if (tid < 256) out[(size_t)b * Uu + col] = hprev;
}

// ---------------------------------------------------------------- launcher
extern "C" void kernel_launch(void* const* d_in, const int* in_sizes, int n_in,
                              void* d_out, int out_size, void* d_ws, size_t ws_size,
                              hipStream_t stream) {
    const float* codes = (const float*)d_in[0];
    const float* W     = (const float*)d_in[1];
    const float* Uk    = (const float*)d_in[2];
    const float* bias  = (const float*)d_in[3];   // [2][768]
    float* out = (float*)d_out;

    char* ws = (char*)d_ws;
    int* len = (int*)ws;
    unsigned char* mask = (unsigned char*)(ws + WS_MASK);
    unsigned int* ukp = (unsigned int*)(ws + WS_UKP);
    uint4* WH4 = (uint4*)(ws + WS_WH);
    uint4* WL4 = (uint4*)(ws + WS_WL);
    _Float16* matx = (_Float16*)(ws + WS_MATX);

    // time-chunk (fp16 matx = CT*393216 B); CT >= 128 for fragment-tile rows
    int CT = 128;
    for (int cc = 512; cc >= 128; cc >>= 1) {
        if (WS_MATX + (size_t)cc * 393216ull <= ws_size) { CT = cc; break; }
    }
    int ctShift = __builtin_ctz((unsigned)CT);
    int nch = 512 / CT;

    zero_len_kernel<<<1, 256, 0, stream>>>(len);
    mask_len_kernel<<<Bb * Tt / 4, 256, 0, stream>>>(codes, mask, len);
    uk_convert_kernel<<<384, 256, 0, stream>>>(Uk, ukp);
    wsplit_kernel<<<96, 256, 0, stream>>>(W, WH4, WL4);

    for (int c = 0; c < nch; ++c) {
        int t0 = c * CT;
        dim3 grid(2 * CT, 6);  // (256*CT/128, 768/128)
        matx_gemm_half<<<grid, 256, 0, stream>>>(codes, WH4, WL4, bias, matx,
                                                 t0, ctShift);
        gru_scan_kernel<<<Bb, 512, 0, stream>>>(matx, ukp, bias + NJ, mask, len,
                                                out, t0, CT);
    }
}